// Round 1
// baseline (745.395 us; speedup 1.0000x reference)
//
#include <hip/hip_runtime.h>
#include <hip/hip_bf16.h>
#include <hip/hip_fp16.h>

#define MUL 32
#define F4 128
#define NB 10
#define NH 100
#define EROW 136   // LDS row stride (ushorts) for sHW: 272 B = 17*16, 16B-aligned rows

#define INV_SQRT32 0.17677669529663687f
#define INV_SQRT10 0.31622776601683794f
#define INV_SQRT100 0.1f
#define INV_SQRT3 0.5773502691896258f
#define AGG_SCALE 0.25f   // 1/sqrt(16)
#define INV8 0.125f       // 1/sqrt(64)
#define C_S 0.3826834323650898f
#define C_X 0.9238795325112867f

typedef __attribute__((ext_vector_type(8))) short short8;
typedef __attribute__((ext_vector_type(4))) float float4v;

__device__ __forceinline__ float bf2f(__hip_bfloat16 v) { return __bfloat162float(v); }
__device__ __forceinline__ unsigned short f2b(float x) {
    __hip_bfloat16 b = __float2bfloat16(x);
    return *(unsigned short*)&b;
}
__device__ __forceinline__ float b2f(unsigned short u) {
    __hip_bfloat16 b;
    *(unsigned short*)&b = u;
    return __bfloat162float(b);
}
// flag: 1 = inputs fp32, 0 = inputs bf16
__device__ __forceinline__ float ldin(const void* p, size_t i, int f) {
    return f ? ((const float*)p)[i] : bf2f(((const __hip_bfloat16*)p)[i]);
}

// packed-f16 atomic add: 2 channels per 32-bit atomic op.
// agg is f16; working set 12.8 MB, write-back 256 B/edge (vs 512 B for f32).
__device__ __forceinline__ void atomic_pk_add_f16(void* p, float lo, float hi) {
    __half2 h = __floats2half2_rn(lo, hi);   // .x = lo = channel c (low 16 bits)
    unsigned int pk = *(unsigned int*)&h;
    asm volatile("global_atomic_pk_add_f16 %0, %1, off"
                 :: "v"((unsigned long long)p), "v"(pk) : "memory");
}

// ---------------------------------------------------------------------------
__global__ void detect_dtype_kernel(const void* __restrict__ node_attr, int* __restrict__ flag) {
    unsigned w = *(const unsigned*)node_attr;
    *flag = (w == 0x3F800000u) ? 1 : 0;
}

// ---------------------------------------------------------------------------
// prep: k-contiguous bf16 B-operands.
// w2t[n(128)][k(128)] (pad k>=100), w20t[v(32)][k(64)], w21t[v(32)][k(64)],
// w1t[n(112)][k(32)] (pad n>=100, k>=10)
// ---------------------------------------------------------------------------
__global__ __launch_bounds__(256) void prep_kernel(
    const void* __restrict__ Wfc1,   // 10 x 100
    const void* __restrict__ Wfc2,   // 100 x 128
    const void* __restrict__ Wl20,   // 64 x 32
    const void* __restrict__ Wl21,   // 64 x 32
    const int* __restrict__ flagp,
    unsigned short* __restrict__ w1t,
    unsigned short* __restrict__ w2t,
    unsigned short* __restrict__ w20t,
    unsigned short* __restrict__ w21t)
{
    int f = *flagp;
    int t = threadIdx.x;
    for (int i = t; i < 128 * 128; i += 256) {
        int n = i >> 7, k = i & 127;
        w2t[i] = (k < NH) ? f2b(ldin(Wfc2, (size_t)k * 128 + n, f)) : 0;
    }
    for (int i = t; i < 32 * 64; i += 256) {
        int v = i >> 6, u = i & 63;
        w20t[i] = f2b(ldin(Wl20, (size_t)u * 32 + v, f));
        w21t[i] = f2b(ldin(Wl21, (size_t)u * 32 + v, f));
    }
    for (int i = t; i < 112 * 32; i += 256) {
        int n = i >> 5, k = i & 31;
        w1t[i] = (k < NB && n < NH) ? f2b(ldin(Wfc1, (size_t)k * NH + n, f)) : 0;
    }
}

// ---------------------------------------------------------------------------
// node_y: y = fctp(x, attr, W_l10, W_l11) -> bf16 [N,128] PLANAR:
// y[n] = [ y0(32) | y1_d0(u:32) | y1_d1(32) | y1_d2(32) ]
// 16 nodes / block.
// ---------------------------------------------------------------------------
__global__ __launch_bounds__(256) void node_y_kernel(
    const void* __restrict__ node_input,
    const void* __restrict__ node_attr,
    const void* __restrict__ Wl10,
    const void* __restrict__ Wl11,
    const int* __restrict__ flagp,
    unsigned short* __restrict__ y, int N)
{
    __shared__ float sW0[1024];
    __shared__ float sW1[1024];
    __shared__ float sX[16 * 128];
    int f = *flagp;
    int t = threadIdx.x;
    for (int i = t; i < 1024; i += 256) {
        sW0[i] = ldin(Wl10, i, f);
        sW1[i] = ldin(Wl11, i, f);
    }
    int n0 = blockIdx.x * 16;
    for (int i = t; i < 2048; i += 256) {
        int ln = i >> 7, c = i & 127, n = n0 + ln;
        sX[i] = (n < N) ? ldin(node_input, (size_t)n * F4 + c, f) : 0.f;
    }
    __syncthreads();
    for (int i = t; i < 2048; i += 256) {
        int ln = i >> 7, c = i & 127, n = n0 + ln;
        if (n >= N) continue;
        float attr = ldin(node_attr, n, f);
        float acc = 0.f;
        if (c < 32) {
#pragma unroll
            for (int u = 0; u < 32; u++) acc += sX[ln * 128 + u] * sW0[u * 32 + c];
        } else {
            int d = (c - 32) >> 5, u0 = (c - 32) & 31;
#pragma unroll
            for (int u = 0; u < 32; u++) acc += sX[ln * 128 + 32 + u * 3 + d] * sW1[u * 32 + u0];
        }
        y[(size_t)n * F4 + c] = f2b(acc * attr * INV_SQRT32);
    }
}

// ---------------------------------------------------------------------------
// Fused edge kernel: 64 edges/block, 256 threads.
// P1: h = silu(ele@W1/sqrt10) via MFMA  -> sHW (A-layout rows, k padded 128)
// P2: w = h@W2 *0.1 via MFMA            -> sHW (aliased; frag-read, barrier, overwrite)
// PC: per-lane A-fragment build (y rows pre-loaded to regs); 16 MFMA proj;
//     16 packed-f16 atomics/lane (channel pairs via shfl_xor lane pairing).
// ---------------------------------------------------------------------------
#define SM_ELEB  0        // ushort[64*32]   4096
#define SM_HW    4096     // ushort[64*136] 17408
#define SM_EA    21504    // float[64*4]     1024
#define SM_SRC   22528    // int[64]          256
#define SM_DST   22784    // int[64]          256
#define SM_TOTAL 23040    // x6 blocks = 138240 (x7 = 161280 also fits 160K... 163840)

__global__ __launch_bounds__(256, 6) void fused_edge_kernel(
    const void* __restrict__ ele,    // E x 10
    const void* __restrict__ eattr,  // E x 4
    const int* __restrict__ esrc,
    const int* __restrict__ edst,
    const int* __restrict__ flagp,
    const unsigned short* __restrict__ y,     // N x 128 bf16 planar
    const unsigned short* __restrict__ w1t,   // 112 x 32
    const unsigned short* __restrict__ w2t,   // 128 x 128
    const unsigned short* __restrict__ w20t,  // 32 x 64
    const unsigned short* __restrict__ w21t,  // 32 x 64
    __half* __restrict__ agg,                 // N x 128 f16
    int E)
{
    __shared__ __align__(16) char smem[SM_TOTAL];
    unsigned short* sEleB = (unsigned short*)(smem + SM_ELEB);
    unsigned short* sHW = (unsigned short*)(smem + SM_HW);
    float* sEa = (float*)(smem + SM_EA);
    int* sSrc = (int*)(smem + SM_SRC);
    int* sDst = (int*)(smem + SM_DST);

    int f = *flagp;
    int t = threadIdx.x;
    int e0 = blockIdx.x * 64;
    int ne = E - e0;
    if (ne > 64) ne = 64;

    // ---- stage ----
    if (t < 64) {
        sSrc[t] = (t < ne) ? esrc[e0 + t] : 0;
        sDst[t] = (t < ne) ? edst[e0 + t] : 0;
    }
    for (int i = t; i < 64 * 32; i += 256) {
        int e = i >> 5, k = i & 31;
        float v = (k < NB && e < ne) ? ldin(ele, (size_t)(e0 + e) * NB + k, f) : 0.f;
        sEleB[i] = f2b(v);
    }
    {
        int e = t >> 2;
        sEa[t] = (e < ne) ? ldin(eattr, (size_t)e0 * 4 + t, f) : 0.f;
    }
    __syncthreads();

    int w = t >> 6, lane = t & 63;
    int lm = lane & 15, quad = lane >> 4;
    int em = w * 16 + lm;

    // ---- y row gather: straight to registers (issued early, hides under P1/P2) ----
    const unsigned short* yrg = y + (size_t)sSrc[em] * 128;
    short8 x0  = *(const short8*)(yrg + quad * 8);
    short8 xd0 = *(const short8*)(yrg + 32 + quad * 8);
    short8 xd1 = *(const short8*)(yrg + 64 + quad * 8);
    short8 xd2 = *(const short8*)(yrg + 96 + quad * 8);

    // ---- P1: GEMM1 + silu -> sHW ----
    {
        short8 a = *(const short8*)(sEleB + (w * 16 + lm) * 32 + quad * 8);
        float4v c1[7];
#pragma unroll
        for (int nt = 0; nt < 7; nt++) {
            c1[nt] = (float4v){0.f, 0.f, 0.f, 0.f};
            short8 b = *(const short8*)(w1t + (nt * 16 + lm) * 32 + quad * 8);
            c1[nt] = __builtin_amdgcn_mfma_f32_16x16x32_bf16(a, b, c1[nt], 0, 0, 0);
        }
#pragma unroll
        for (int nt = 0; nt < 7; nt++) {
            int ch = nt * 16 + lm;
#pragma unroll
            for (int r = 0; r < 4; r++) {
                int row = w * 16 + quad * 4 + r;
                float hv = 0.f;
                if (ch < NH) {
                    float aa = c1[nt][r] * INV_SQRT10;
                    hv = aa / (1.f + __expf(-aa));
                }
                sHW[row * EROW + ch] = f2b(hv);
            }
        }
        // zero k in [112,128)
        int e = t >> 2, seg = t & 3;
        *(uint2*)(sHW + e * EROW + 112 + seg * 4) = (uint2){0u, 0u};
    }
    __syncthreads();

    // ---- P2: GEMM2 (read h frags, barrier, overwrite with wout) ----
    short8 a2[4];
#pragma unroll
    for (int kc = 0; kc < 4; kc++)
        a2[kc] = *(const short8*)(sHW + (w * 16 + lm) * EROW + kc * 32 + quad * 8);
    __syncthreads();
    {
        float4v c2[8];
#pragma unroll
        for (int nt = 0; nt < 8; nt++) c2[nt] = (float4v){0.f, 0.f, 0.f, 0.f};
#pragma unroll
        for (int kc = 0; kc < 4; kc++) {
#pragma unroll
            for (int nt = 0; nt < 8; nt++) {
                short8 b = *(const short8*)(w2t + (nt * 16 + lm) * 128 + kc * 32 + quad * 8);
                c2[nt] = __builtin_amdgcn_mfma_f32_16x16x32_bf16(a2[kc], b, c2[nt], 0, 0, 0);
            }
        }
#pragma unroll
        for (int nt = 0; nt < 8; nt++)
#pragma unroll
            for (int r = 0; r < 4; r++)
                sHW[(w * 16 + quad * 4 + r) * EROW + nt * 16 + lm] = f2b(c2[nt][r] * INV_SQRT100);
    }
    __syncthreads();

    // ---- PC: build A-frags in regs, project via MFMA, packed-f16 atomics ----
    {
        const unsigned short* wr = sHW + em * EROW;
        short8 wA = *(const short8*)(wr + quad * 8);
        short8 wB = *(const short8*)(wr + 32 + quad * 8);
        short8 wC = *(const short8*)(wr + 64 + quad * 8);
        short8 wD = *(const short8*)(wr + 96 + quad * 8);
        float ea0 = sEa[em * 4 + 0];
        float e1x = sEa[em * 4 + 1];
        float e1y = sEa[em * 4 + 2];
        float e1z = sEa[em * 4 + 3];
        float ea0S = ea0 * AGG_SCALE;
        float s3 = AGG_SCALE * INV_SQRT3;

        short8 f00, f01, f10, f11, f20, f21, f30, f31;
#pragma unroll
        for (int j = 0; j < 8; j++) {
            float x0f = b2f((unsigned short)x0[j]);
            float d0f = b2f((unsigned short)xd0[j]);
            float d1f = b2f((unsigned short)xd1[j]);
            float d2f = b2f((unsigned short)xd2[j]);
            f00[j] = (short)f2b(b2f((unsigned short)wA[j]) * x0f * ea0S);
            float tt = d0f * e1x + d1f * e1y + d2f * e1z;
            f01[j] = (short)f2b(b2f((unsigned short)wD[j]) * tt * s3);
            float p = b2f((unsigned short)wB[j]) * x0f * AGG_SCALE;
            f10[j] = (short)f2b(p * e1x);
            f20[j] = (short)f2b(p * e1y);
            f30[j] = (short)f2b(p * e1z);
            float q = b2f((unsigned short)wC[j]) * ea0S;
            f11[j] = (short)f2b(q * d0f);
            f21[j] = (short)f2b(q * d1f);
            f31[j] = (short)f2b(q * d2f);
        }

        float4v acc[8];
#pragma unroll
        for (int i = 0; i < 8; i++) acc[i] = (float4v){0.f, 0.f, 0.f, 0.f};
#pragma unroll
        for (int g = 0; g < 4; g++) {
            const unsigned short* wt = g ? w21t : w20t;
            short8 ak0 = (g == 0) ? f00 : (g == 1) ? f10 : (g == 2) ? f20 : f30;
            short8 ak1 = (g == 0) ? f01 : (g == 1) ? f11 : (g == 2) ? f21 : f31;
#pragma unroll
            for (int nt = 0; nt < 2; nt++) {
                short8 b0 = *(const short8*)(wt + (nt * 16 + lm) * 64 + quad * 8);
                short8 b1 = *(const short8*)(wt + (nt * 16 + lm) * 64 + 32 + quad * 8);
                acc[g * 2 + nt] = __builtin_amdgcn_mfma_f32_16x16x32_bf16(ak0, b0, acc[g * 2 + nt], 0, 0, 0);
                acc[g * 2 + nt] = __builtin_amdgcn_mfma_f32_16x16x32_bf16(ak1, b1, acc[g * 2 + nt], 0, 0, 0);
            }
        }

        // C-layout: lane lm holds channel chbase+lm for edge rows w*16+quad*4+r.
        // Lane pair (lm, lm^1) holds channels (c, c+1) of the SAME edges ->
        // exchange via shfl_xor, even lanes emit rows {0,1}, odd lanes rows {2,3}
        // as packed half2 atomics. 16 pk-atomics/thread (was 32 f32 atomics).
        bool oddl = (lm & 1);
#pragma unroll
        for (int i = 0; i < 8; i++) {
            int g = i >> 1, nt = i & 1;
            int chbase = (g == 0) ? (nt * 16) : (32 + (g - 1) * 32 + nt * 16);
            float p0 = __shfl_xor(acc[i][0], 1);
            float p1 = __shfl_xor(acc[i][1], 1);
            float p2 = __shfl_xor(acc[i][2], 1);
            float p3 = __shfl_xor(acc[i][3], 1);
            float lo0 = oddl ? p2 : acc[i][0];
            float hi0 = oddl ? acc[i][2] : p0;
            float lo1 = oddl ? p3 : acc[i][1];
            float hi1 = oddl ? acc[i][3] : p1;
            int r0 = oddl ? 2 : 0;
            int er0 = w * 16 + quad * 4 + r0;
            int er1 = er0 + 1;
            int pc = chbase + (lm & ~1);
            if (er0 < ne)
                atomic_pk_add_f16(agg + (size_t)sDst[er0] * F4 + pc, lo0, hi0);
            if (er1 < ne)
                atomic_pk_add_f16(agg + (size_t)sDst[er1] * F4 + pc, lo1, hi1);
        }
        // inline-asm atomics are invisible to the compiler's vmcnt tracking:
        // drain before endpgm so no wave retires with atomics in flight.
        asm volatile("s_waitcnt vmcnt(0)" ::: "memory");
    }
}

// ---------------------------------------------------------------------------
// out: out = attr*(c_s * sc(x) + c_x * agg * INV8); 16 nodes/block
// agg (f16) layout: c<32 -> z0[c]; z1[u][d] at 32 + d*32 + u
// ---------------------------------------------------------------------------
__global__ __launch_bounds__(256) void out_kernel(
    const void* __restrict__ node_input,
    const void* __restrict__ node_attr,
    const void* __restrict__ Wsc0,
    const void* __restrict__ Wsc1,
    const __half* __restrict__ agg,   // N x 128 f16
    const int* __restrict__ flagp,
    void* __restrict__ out, int N)
{
    __shared__ float sWs0[1024], sWs1[1024];
    __shared__ float sX[16 * 128];
    __shared__ float sA[16 * 128];
    int f = *flagp;
    int t = threadIdx.x;
    for (int i = t; i < 1024; i += 256) {
        sWs0[i] = ldin(Wsc0, i, f);
        sWs1[i] = ldin(Wsc1, i, f);
    }
    int n0 = blockIdx.x * 16;
    for (int i = t; i < 2048; i += 256) {
        int ln = i >> 7, c = i & 127, n = n0 + ln;
        sX[i] = (n < N) ? ldin(node_input, (size_t)n * F4 + c, f) : 0.f;
        sA[i] = (n < N) ? __half2float(agg[(size_t)n * F4 + c]) : 0.f;
    }
    __syncthreads();
    for (int i = t; i < 2048; i += 256) {
        int ln = i >> 7, c = i & 127, n = n0 + ln;
        if (n >= N) continue;
        float attr = ldin(node_attr, n, f);
        float s, z;
        if (c < 32) {
            float as = 0.f;
#pragma unroll
            for (int u = 0; u < 32; u++) as += sX[ln * 128 + u] * sWs0[u * 32 + c];
            s = as * INV_SQRT32;
            z = sA[ln * 128 + c];
        } else {
            int i2 = c - 32;
            int u0 = i2 / 3, d = i2 - u0 * 3;
            float as = 0.f;
#pragma unroll
            for (int u = 0; u < 32; u++) as += sX[ln * 128 + 32 + u * 3 + d] * sWs1[u * 32 + u0];
            s = as * INV_SQRT32;
            z = sA[ln * 128 + 32 + d * 32 + u0];
        }
        float val = attr * (C_S * s + C_X * z * INV8);
        size_t oi = (size_t)n * F4 + c;
        if (f) ((float*)out)[oi] = val;
        else   ((__hip_bfloat16*)out)[oi] = __float2bfloat16(val);
    }
}

// ---------------------------------------------------------------------------
extern "C" void kernel_launch(void* const* d_in, const int* in_sizes, int n_in,
                              void* d_out, int out_size, void* d_ws, size_t ws_size,
                              hipStream_t stream) {
    const void* node_input = d_in[0];
    const void* node_attr  = d_in[1];
    const int* edge_src    = (const int*)d_in[2];
    const int* edge_dst    = (const int*)d_in[3];
    const void* edge_attr  = d_in[4];
    const void* ele        = d_in[5];
    const void* Wsc0       = d_in[6];
    const void* Wsc1       = d_in[7];
    const void* Wl10       = d_in[8];
    const void* Wl11       = d_in[9];
    const void* Wl20       = d_in[10];
    const void* Wl21       = d_in[11];
    const void* Wfc1       = d_in[12];
    const void* Wfc2       = d_in[13];

    int N = in_sizes[0] / F4;   // 50000
    int E = in_sizes[2];        // 800000

    char* ws = (char*)d_ws;
    int* flag = (int*)ws;                                        // 64 B
    unsigned short* y = (unsigned short*)(ws + 64);              // N*128 bf16
    size_t y_b = (size_t)N * F4 * 2;
    __half* agg = (__half*)(ws + 64 + y_b);                      // N*128 f16
    size_t agg_b = (size_t)N * F4 * 2;
    size_t off = 64 + y_b + agg_b;
    unsigned short* w2t  = (unsigned short*)(ws + off);          // 32 KB
    unsigned short* w20t = (unsigned short*)(ws + off + 32768);  // 4 KB
    unsigned short* w21t = (unsigned short*)(ws + off + 36864);  // 4 KB
    unsigned short* w1t  = (unsigned short*)(ws + off + 40960);  // 7 KB

    detect_dtype_kernel<<<1, 1, 0, stream>>>(node_attr, flag);
    prep_kernel<<<1, 256, 0, stream>>>(Wfc1, Wfc2, Wl20, Wl21, flag, w1t, w2t, w20t, w21t);
    hipMemsetAsync(agg, 0, agg_b, stream);

    node_y_kernel<<<(N + 15) / 16, 256, 0, stream>>>(node_input, node_attr, Wl10, Wl11, flag, y, N);

    fused_edge_kernel<<<(E + 63) / 64, 256, 0, stream>>>(
        ele, edge_attr, edge_src, edge_dst, flag, y, w1t, w2t, w20t, w21t, agg, E);

    out_kernel<<<(N + 15) / 16, 256, 0, stream>>>(node_input, node_attr, Wsc0, Wsc1,
                                                  agg, flag, d_out, N);
}